// Round 1
// baseline (824.251 us; speedup 1.0000x reference)
//
#include <hip/hip_runtime.h>
#include <hip/hip_bf16.h>
#include <math.h>

#define B_ 32
#define H_ 32
#define KV_ 8
#define G_ 4
#define S_ 4096
#define D_ 64
#define HID_ 2048
#define FF_ 8192
#define V_ 32000
#define SPLIT_ 4
#define CHUNK_ (S_ / SPLIT_)   // 1024

typedef float f32x4 __attribute__((ext_vector_type(4)));
typedef short s16x8 __attribute__((ext_vector_type(8)));

__device__ __forceinline__ ushort f2bf(float f) {
    uint u = __builtin_bit_cast(uint, f);
    u = (u + 0x7FFFu + ((u >> 16) & 1u)) >> 16;
    return (ushort)u;
}

__device__ __forceinline__ float gelu_exact(float x) {
    return 0.5f * x * (1.f + erff(x * 0.70710678118654752f));
}

// ---------------------------------------------------------------------------
// K1: attention partials. grid = B*KV*SPLIT = 1024 blocks, 256 threads.
// Each block: one (b, kv, s-chunk); computes G=4 heads sharing this K/V.
// ---------------------------------------------------------------------------
__global__ __launch_bounds__(256) void attn_partial(
    const float* __restrict__ q, const float* __restrict__ ks,
    const float* __restrict__ vs,
    float* __restrict__ pm, float* __restrict__ pl, float* __restrict__ pacc)
{
    const int blk = blockIdx.x;
    const int sp = blk & (SPLIT_ - 1);
    const int kv = (blk >> 2) & (KV_ - 1);
    const int b  = blk >> 5;

    const int tid = threadIdx.x;
    const int w  = tid >> 6;    // wave 0..3
    const int l  = tid & 63;
    const int jj = l >> 4;      // 0..3: row-in-group
    const int c  = l & 15;      // 0..15: 4-float slice of D=64

    __shared__ float sc[CHUNK_ * G_];       // scores, 16 KB
    __shared__ float acc_s[G_ * D_];
    __shared__ float l_s[G_];
    __shared__ float m_s[G_];

    // q fragments in registers: qr[g][i] covers d = c*4 + i
    float qr[G_][4];
    #pragma unroll
    for (int g = 0; g < G_; ++g) {
        const float* qp = q + ((size_t)(b * H_ + kv * G_ + g)) * D_ + c * 4;
        f32x4 t = *(const f32x4*)qp;
        qr[g][0] = t[0]; qr[g][1] = t[1]; qr[g][2] = t[2]; qr[g][3] = t[3];
    }

    // ---- pass 1: scores ----
    const float* Kbase = ks + ((size_t)(b * KV_ + kv) * S_ + sp * CHUNK_) * D_;
    const float scl = 0.125f;  // 1/sqrt(64)
    for (int it = 0; it < CHUNK_ / 16; ++it) {
        const int jr = it * 16 + w * 4 + jj;
        f32x4 kr = *(const f32x4*)(Kbase + (size_t)jr * D_ + c * 4);
        float p[G_];
        #pragma unroll
        for (int g = 0; g < G_; ++g)
            p[g] = kr[0]*qr[g][0] + kr[1]*qr[g][1] + kr[2]*qr[g][2] + kr[3]*qr[g][3];
        #pragma unroll
        for (int m = 1; m < 16; m <<= 1) {
            #pragma unroll
            for (int g = 0; g < G_; ++g) p[g] += __shfl_xor(p[g], m);
        }
        #pragma unroll
        for (int g = 0; g < G_; ++g)
            if (c == g) sc[jr * G_ + g] = p[g] * scl;
    }
    for (int i = tid; i < G_ * D_; i += 256) acc_s[i] = 0.f;
    if (tid < G_) l_s[tid] = 0.f;
    __syncthreads();

    // ---- chunk max per head ----
    {
        const int g = tid >> 6;   // 4 waves -> 4 heads
        float m = -1e30f;
        for (int u = l; u < CHUNK_; u += 64) m = fmaxf(m, sc[u * G_ + g]);
        #pragma unroll
        for (int k = 1; k < 64; k <<= 1) m = fmaxf(m, __shfl_xor(m, k));
        if (l == 0) m_s[g] = m;
    }
    __syncthreads();
    float M[G_];
    #pragma unroll
    for (int g = 0; g < G_; ++g) M[g] = m_s[g];

    // ---- pass 2: exp, sum, V accumulate ----
    const float* Vbase = vs + ((size_t)(b * KV_ + kv) * S_ + sp * CHUNK_) * D_;
    float va[G_][4];
    #pragma unroll
    for (int g = 0; g < G_; ++g) { va[g][0]=va[g][1]=va[g][2]=va[g][3]=0.f; }
    float ll[G_] = {0.f, 0.f, 0.f, 0.f};

    for (int it = 0; it < CHUNK_ / 16; ++it) {
        const int jr = it * 16 + w * 4 + jj;
        f32x4 vv = *(const f32x4*)(Vbase + (size_t)jr * D_ + c * 4);
        #pragma unroll
        for (int g = 0; g < G_; ++g) {
            const float wgt = __expf(sc[jr * G_ + g] - M[g]);
            ll[g] += (c == 0) ? wgt : 0.f;
            va[g][0] += wgt * vv[0];
            va[g][1] += wgt * vv[1];
            va[g][2] += wgt * vv[2];
            va[g][3] += wgt * vv[3];
        }
    }
    // reduce over jj (lanes +-16, +-32)
    #pragma unroll
    for (int k = 16; k < 64; k <<= 1) {
        #pragma unroll
        for (int g = 0; g < G_; ++g) {
            #pragma unroll
            for (int i = 0; i < 4; ++i) va[g][i] += __shfl_xor(va[g][i], k);
            ll[g] += __shfl_xor(ll[g], k);
        }
    }
    if (jj == 0) {
        #pragma unroll
        for (int g = 0; g < G_; ++g) {
            #pragma unroll
            for (int i = 0; i < 4; ++i)
                atomicAdd(&acc_s[g * D_ + c * 4 + i], va[g][i]);
            if (c == 0) atomicAdd(&l_s[g], ll[g]);
        }
    }
    __syncthreads();

    // ---- write partials ----
    const int basew = (b * KV_ + kv) * G_ * SPLIT_;
    if (tid < G_) {
        pm[basew + tid * SPLIT_ + sp] = m_s[tid];
        pl[basew + tid * SPLIT_ + sp] = l_s[tid];
    }
    {
        const int g = tid >> 6;
        const int d = tid & 63;
        pacc[(size_t)(basew + g * SPLIT_ + sp) * D_ + d] = acc_s[g * D_ + d];
    }
}

// ---------------------------------------------------------------------------
// K2: combine split-S partials -> ctx bf16 [32][2048]. grid = B*H, 64 thr.
// ---------------------------------------------------------------------------
__global__ __launch_bounds__(64) void attn_combine(
    const float* __restrict__ pm, const float* __restrict__ pl,
    const float* __restrict__ pacc, ushort* __restrict__ ctx)
{
    const int hb = blockIdx.x;
    const int d = threadIdx.x;
    const int b = hb >> 5;
    const int h = hb & 31;
    const int kv = h >> 2;
    const int g = h & 3;
    const int base = ((b * KV_ + kv) * G_ + g) * SPLIT_;

    float M = -1e30f;
    #pragma unroll
    for (int sp = 0; sp < SPLIT_; ++sp) M = fmaxf(M, pm[base + sp]);
    float L = 0.f, o = 0.f;
    #pragma unroll
    for (int sp = 0; sp < SPLIT_; ++sp) {
        const float f = __expf(pm[base + sp] - M);
        L += pl[base + sp] * f;
        o += pacc[(size_t)(base + sp) * D_ + d] * f;
    }
    ctx[(size_t)b * HID_ + h * D_ + d] = f2bf(o / L);
}

// ---------------------------------------------------------------------------
// Skinny GEMM: out[32][N] = A[32][K](bf16) @ W[N][K]^T(fp32, cvt to bf16)
// grid.x over N/64, grid.y = SK (split-K). 256 threads = 4 waves x 16 cols.
// epi: 0 = +bias +add -> fp32   (only when SK==1)
//      1 = +bias, gelu -> bf16  (only when SK==1)
//      2 = plain -> fp32        (only when SK==1)
//      3 = raw partial -> part[sk][32][N]
// ---------------------------------------------------------------------------
__global__ __launch_bounds__(256) void gemm_skinny(
    const ushort* __restrict__ A, const float* __restrict__ W,
    const float* __restrict__ bias, const float* __restrict__ add,
    float* __restrict__ outf, ushort* __restrict__ outb,
    float* __restrict__ part, int N, int K, int SK, int epi)
{
    const int l = threadIdx.x & 63;
    const int wv = threadIdx.x >> 6;
    const int nb = blockIdx.x * 64 + wv * 16;
    const int col = nb + (l & 15);
    const int kr = (l >> 4) * 8;
    const int sk = blockIdx.y;
    const int kslice = K / SK;
    const int kstart = sk * kslice;

    f32x4 acc0 = {0.f, 0.f, 0.f, 0.f};
    f32x4 acc1 = {0.f, 0.f, 0.f, 0.f};

    const float*  wp = W + (size_t)col * K + kstart + kr;
    const ushort* a0 = A + (size_t)(l & 15) * K + kstart + kr;
    const ushort* a1 = a0 + (size_t)16 * K;

    for (int k0 = 0; k0 < kslice; k0 += 32) {
        f32x4 w0 = *(const f32x4*)(wp);
        f32x4 w1 = *(const f32x4*)(wp + 4);
        s16x8 bf;
        bf[0] = (short)f2bf(w0[0]); bf[1] = (short)f2bf(w0[1]);
        bf[2] = (short)f2bf(w0[2]); bf[3] = (short)f2bf(w0[3]);
        bf[4] = (short)f2bf(w1[0]); bf[5] = (short)f2bf(w1[1]);
        bf[6] = (short)f2bf(w1[2]); bf[7] = (short)f2bf(w1[3]);
        s16x8 af0 = *(const s16x8*)(a0);
        s16x8 af1 = *(const s16x8*)(a1);
        acc0 = __builtin_amdgcn_mfma_f32_16x16x32_bf16(af0, bf, acc0, 0, 0, 0);
        acc1 = __builtin_amdgcn_mfma_f32_16x16x32_bf16(af1, bf, acc1, 0, 0, 0);
        wp += 32; a0 += 32; a1 += 32;
    }

    const float bs = (bias != nullptr) ? bias[col] : 0.f;
    #pragma unroll
    for (int i = 0; i < 4; ++i) {
        const int m0 = (l >> 4) * 4 + i;          // C layout: row=(l>>4)*4+i, col=l&15
        const float v0 = acc0[i] + bs;
        const float v1 = acc1[i] + bs;
        const size_t i0 = (size_t)m0 * N + col;
        const size_t i1 = (size_t)(m0 + 16) * N + col;
        if (epi == 0) {
            outf[i0] = v0 + add[i0];
            outf[i1] = v1 + add[i1];
        } else if (epi == 1) {
            outb[i0] = f2bf(gelu_exact(v0));
            outb[i1] = f2bf(gelu_exact(v1));
        } else if (epi == 2) {
            outf[i0] = v0;
            outf[i1] = v1;
        } else {
            part[(size_t)sk * 32 * N + i0] = acc0[i];
            part[(size_t)sk * 32 * N + i1] = acc1[i];
        }
    }
}

// ---------------------------------------------------------------------------
// Reduce split-K partials + epilogue. grid over 32*N / 256.
// epi: 0 = +bias +add -> fp32 ; 1 = +bias, gelu -> bf16
// ---------------------------------------------------------------------------
__global__ __launch_bounds__(256) void reduce_epi_k(
    const float* __restrict__ part, const float* __restrict__ bias,
    const float* __restrict__ add, float* __restrict__ outf,
    ushort* __restrict__ outb, int N, int SK, int epi)
{
    const int idx = blockIdx.x * 256 + threadIdx.x;
    const int total = 32 * N;
    if (idx >= total) return;
    const int n = idx % N;
    float v = 0.f;
    for (int sk = 0; sk < SK; ++sk) v += part[(size_t)sk * total + idx];
    v += bias[n];
    if (epi == 0) outf[idx] = v + add[idx];
    else          outb[idx] = f2bf(gelu_exact(v));
}

// ---------------------------------------------------------------------------
// LayerNorm over rows of [32][2048] fp32 -> bf16. grid=32, 256 threads.
// ---------------------------------------------------------------------------
__global__ __launch_bounds__(256) void layernorm_k(
    const float* __restrict__ x, const float* __restrict__ g,
    const float* __restrict__ b, ushort* __restrict__ out)
{
    const int row = blockIdx.x;
    const float* xr = x + (size_t)row * HID_;
    const int t = threadIdx.x;

    f32x4 v0 = *(const f32x4*)(xr + t * 4);
    f32x4 v1 = *(const f32x4*)(xr + 1024 + t * 4);
    float s = v0[0]+v0[1]+v0[2]+v0[3] + v1[0]+v1[1]+v1[2]+v1[3];
    float qq = v0[0]*v0[0]+v0[1]*v0[1]+v0[2]*v0[2]+v0[3]*v0[3]
             + v1[0]*v1[0]+v1[1]*v1[1]+v1[2]*v1[2]+v1[3]*v1[3];

    __shared__ float ss[4], sq[4];
    #pragma unroll
    for (int k = 1; k < 64; k <<= 1) {
        s  += __shfl_xor(s, k);
        qq += __shfl_xor(qq, k);
    }
    if ((t & 63) == 0) { ss[t >> 6] = s; sq[t >> 6] = qq; }
    __syncthreads();
    const float S = ss[0] + ss[1] + ss[2] + ss[3];
    const float Q = sq[0] + sq[1] + sq[2] + sq[3];
    const float mean = S * (1.f / HID_);
    const float var = Q * (1.f / HID_) - mean * mean;
    const float rstd = rsqrtf(var + 1e-5f);

    ushort* orow = out + (size_t)row * HID_;
    #pragma unroll
    for (int i = 0; i < 4; ++i) {
        const int i0 = t * 4 + i;
        const int i1 = i0 + 1024;
        orow[i0] = f2bf((v0[i] - mean) * rstd * g[i0] + b[i0]);
        orow[i1] = f2bf((v1[i] - mean) * rstd * g[i1] + b[i1]);
    }
}

// ---------------------------------------------------------------------------
extern "C" void kernel_launch(void* const* d_in, const int* in_sizes, int n_in,
                              void* d_out, int out_size, void* d_ws, size_t ws_size,
                              hipStream_t stream) {
    const float* residual = (const float*)d_in[0];
    const float* q        = (const float*)d_in[1];
    const float* ks       = (const float*)d_in[2];
    const float* vs       = (const float*)d_in[3];
    const float* Wo       = (const float*)d_in[4];
    const float* bo       = (const float*)d_in[5];
    const float* g2       = (const float*)d_in[6];
    const float* b2       = (const float*)d_in[7];
    const float* W1       = (const float*)d_in[8];
    const float* b1       = (const float*)d_in[9];
    const float* W2       = (const float*)d_in[10];
    const float* b2m      = (const float*)d_in[11];
    const float* gf       = (const float*)d_in[12];
    const float* bf       = (const float*)d_in[13];
    const float* Wlm      = (const float*)d_in[14];
    float* logits = (float*)d_out;

    char* ws = (char*)d_ws;
    // ws layout (bytes)
    float*  pm   = (float*) (ws + 0);                      // 16 KB
    float*  pl   = (float*) (ws + 16384);                  // 16 KB
    float*  pacc = (float*) (ws + 32768);                  // 1 MB
    ushort* ctx  = (ushort*)(ws + 1081344);                // 128 KB
    float*  h    = (float*) (ws + 1212416);                // 256 KB
    ushort* hn   = (ushort*)(ws + 1474560);                // 128 KB
    ushort* a2   = (ushort*)(ws + 1605632);                // 512 KB
    float*  h2   = (float*) (ws + 2129920);                // 256 KB
    ushort* hf   = (ushort*)(ws + 2392064);                // 128 KB
    float*  part = (float*) (ws + 2523136);                // 2 MB

    // 1. attention partials
    attn_partial<<<B_ * KV_ * SPLIT_, 256, 0, stream>>>(q, ks, vs, pm, pl, pacc);
    // 2. combine -> ctx bf16
    attn_combine<<<B_ * H_, 64, 0, stream>>>(pm, pl, pacc, ctx);
    // 3. attn_out = ctx @ Wo^T + bo + residual  (split-K 8)
    gemm_skinny<<<dim3(HID_ / 64, 8), 256, 0, stream>>>(
        ctx, Wo, nullptr, nullptr, nullptr, nullptr, part, HID_, HID_, 8, 3);
    reduce_epi_k<<<(32 * HID_) / 256, 256, 0, stream>>>(
        part, bo, residual, h, nullptr, HID_, 8, 0);
    // 4. LN1 -> hn bf16
    layernorm_k<<<32, 256, 0, stream>>>(h, g2, b2, hn);
    // 5. mid = gelu(hn @ W1^T + b1) -> a2 bf16  (split-K 2)
    gemm_skinny<<<dim3(FF_ / 64, 2), 256, 0, stream>>>(
        hn, W1, nullptr, nullptr, nullptr, nullptr, part, FF_, HID_, 2, 3);
    reduce_epi_k<<<(32 * FF_) / 256, 256, 0, stream>>>(
        part, b1, nullptr, nullptr, a2, FF_, 2, 1);
    // 6. h2 = a2 @ W2^T + b2m + h  (split-K 8)
    gemm_skinny<<<dim3(HID_ / 64, 8), 256, 0, stream>>>(
        a2, W2, nullptr, nullptr, nullptr, nullptr, part, HID_, FF_, 8, 3);
    reduce_epi_k<<<(32 * HID_) / 256, 256, 0, stream>>>(
        part, b2m, h, h2, nullptr, HID_, 8, 0);
    // 7. LN2 -> hf bf16
    layernorm_k<<<32, 256, 0, stream>>>(h2, gf, bf, hf);
    // 8. logits = hf @ Wlm^T
    gemm_skinny<<<dim3(V_ / 64, 1), 256, 0, stream>>>(
        hf, Wlm, nullptr, nullptr, logits, nullptr, nullptr, V_, HID_, 1, 2);
}